// Round 18
// baseline (127.908 us; speedup 1.0000x reference)
//
#include <hip/hip_runtime.h>
#include <hip/hip_bf16.h>
#include <math.h>

#define AUDIO_LEN 1310720
#define NBATCH    16
#define NFRAMES   2561
#define NT        (NBATCH * NFRAMES)   // 40976
#define NHALF     (NT / 2)             // 20488 frames per A/B dispatch
#define NFFT      2048
#define HALF_N    1024
#define NK        84
#define NF        1025
#define MROW      1056                 // padded mag row stride (f16)
#define NCH       33                   // weight table extent (33*32 = 1056)
#define NCH_USED  18                   // f >= 576 skipped (w_83 <= 1.7e-4)
#define NSU       9                    // untangle bins t+64s, s<9 -> 0..575

// ws layout: float offsets for tables, byte offset for mag
#define TW_OFF   0                     // float2[1025]: TW[k] = e^{-i pi k/1024}
#define WIN_OFF  2052                  // float[2048]  (pre-scaled by 0.25)
#define TP0_OFF  4100                  // float2[15*64]: W_1024^{t*(i+1)}
#define WF_OFF   6144                  // _Float16[33*512*8] pre-fragmented W
#define MAG_OFF_B 294912               // f16 mag[NT][MROW], 16B aligned

typedef _Float16 h8    __attribute__((ext_vector_type(8)));
typedef float    f32x4 __attribute__((ext_vector_type(4)));
typedef float    f2    __attribute__((ext_vector_type(2)));

__device__ __forceinline__ void gll16(const void* src, void* dst) {
    __builtin_amdgcn_global_load_lds(
        (const __attribute__((address_space(1))) void*)src,
        (__attribute__((address_space(3))) void*)dst, 16, 0, 0);
}

// packed complex mul
__device__ __forceinline__ f2 cmul(f2 a, f2 b) {
    f2 t = a.yy * b.yx;        // {ay*by, ay*bx}
    f2 m; m.x = -t.x; m.y = t.y;
    return a.xx * b + m;       // pk_fma
}

#define DFT4V(p0, p1, p2, p3, y0, y1, y2, y3) do {                       \
    const f2 u0 = (p0) + (p2), u1 = (p0) - (p2);                         \
    const f2 u2 = (p1) + (p3), u3 = (p1) - (p3);                         \
    f2 r; r.x = u3.y; r.y = -u3.x;        /* -i * u3 */                  \
    (y0) = u0 + u2; (y2) = u0 - u2;                                      \
    (y1) = u1 + r;  (y3) = u1 - r;                                       \
} while (0)

// DFT-16 in registers: two radix-4 levels + constant omega16 twiddles
__device__ __forceinline__ void dft16v(f2* v) {
    const float C = 0.92387953251128674f;   // cos(pi/8)
    const float S = 0.38268343236508978f;   // sin(pi/8)
    const float H = 0.70710678118654752f;
    const f2 W1 = {C, -S}, W2c = {H, -H}, W3 = {S, -C}, W6 = {-H, -H}, W9 = {-C, S};
    f2 A[16];
#pragma unroll
    for (int b = 0; b < 4; b++)
        DFT4V(v[b], v[b + 4], v[b + 8], v[b + 12],
              A[b * 4 + 0], A[b * 4 + 1], A[b * 4 + 2], A[b * 4 + 3]);
    A[5]  = cmul(A[5],  W1);
    A[6]  = cmul(A[6],  W2c);
    A[7]  = cmul(A[7],  W3);
    A[9]  = cmul(A[9],  W2c);
    { f2 r; r.x = A[10].y; r.y = -A[10].x; A[10] = r; }   // * -i
    A[11] = cmul(A[11], W6);
    A[13] = cmul(A[13], W3);
    A[14] = cmul(A[14], W6);
    A[15] = cmul(A[15], W9);
#pragma unroll
    for (int d1 = 0; d1 < 4; d1++)
        DFT4V(A[0 + d1], A[4 + d1], A[8 + d1], A[12 + d1],
              v[d1], v[d1 + 4], v[d1 + 8], v[d1 + 12]);
}

// v[i] *= w1^i, i=1..15 (packed power tree; zero memory traffic)
__device__ __forceinline__ void twiddle15v(f2* v, f2 w1) {
    f2 wp[16];
    wp[1]  = w1;
    wp[2]  = cmul(w1, w1);
    wp[3]  = cmul(wp[2], w1);
    wp[4]  = cmul(wp[2], wp[2]);
    wp[5]  = cmul(wp[4], w1);
    wp[6]  = cmul(wp[3], wp[3]);
    wp[7]  = cmul(wp[4], wp[3]);
    wp[8]  = cmul(wp[4], wp[4]);
    wp[9]  = cmul(wp[8], w1);
    wp[10] = cmul(wp[5], wp[5]);
    wp[11] = cmul(wp[8], wp[3]);
    wp[12] = cmul(wp[6], wp[6]);
    wp[13] = cmul(wp[8], wp[5]);
    wp[14] = cmul(wp[7], wp[7]);
    wp[15] = cmul(wp[8], wp[7]);
#pragma unroll
    for (int i = 1; i < 16; i++) v[i] = cmul(v[i], wp[i]);
}

__global__ __launch_bounds__(256) void init_tables_kernel(float* __restrict__ ws) {
    int i = blockIdx.x * 256 + threadIdx.x;
    // pre-fragmented f16 weights: [ck][slot=mt*64+lane (384..511 zero-pad)][8]
    if (i < NCH * 512 * 8) {
        int i8 = i & 7;
        int c  = i >> 3;
        int ck = c >> 9;
        int cc = c & 511;
        int mt = cc >> 6;
        int l  = cc & 63;
        int k  = mt * 16 + (l & 15);
        int f  = ck * 32 + (l >> 4) * 8 + i8;
        float w = 0.0f;
        if (cc < 384 && k < NK && f < NF) {
            float sf = (float)f * (22050.0f / 2048.0f);
            float cf = 27.5f * exp2f((float)k * (1.0f / 12.0f));
            w = expf(-fabsf(sf - cf) / (0.1f * cf));
        }
        ((_Float16*)(ws + WF_OFF))[i] = (_Float16)w;
    }
    if (i <= HALF_N) {
        double ang = -2.0 * M_PI * (double)i / 2048.0;
        ws[TW_OFF + 2 * i]     = (float)cos(ang);
        ws[TW_OFF + 2 * i + 1] = (float)sin(ang);
    }
    if (i < NFFT) {
        double ang = 2.0 * M_PI * (double)i / 2048.0;
        ws[WIN_OFF + i] = (float)(0.25 * (1.0 - cos(ang)));   // 0.5*Hann: folds mag 0.5
    }
    if (i < 960) {   // TP0[ip][t] = W_1024^{t*(ip+1)}, f64-exact
        int ip = i >> 6, tt = i & 63;
        double ang = -2.0 * M_PI * (double)(tt * (ip + 1)) / 1024.0;
        ws[TP0_OFF + 2 * i]     = (float)cos(ang);
        ws[TP0_OFF + 2 * i + 1] = (float)sin(ang);
    }
}

// ======== A/B variant 1: in-register twiddle power trees (R17 structure) ========
__global__ __launch_bounds__(128) void fft_tree(const float* __restrict__ audio,
                                                const float* __restrict__ ws,
                                                _Float16* __restrict__ mag,
                                                int ft_base) {
    __shared__ f2 Abuf[2][HALF_N];     // 8 KB per wave, wave-private

    const int t    = threadIdx.x & 63;
    const int wave = threadIdx.x >> 6;
    const int ft   = ft_base + blockIdx.x * 2 + wave;
    const int b    = ft / NFRAMES;
    const int tf   = ft - b * NFRAMES;
    f2* __restrict__ A = Abuf[wave];

    const f2* __restrict__ TWv = (const f2*)(ws + TW_OFF);
    const f2* __restrict__ W2v = (const f2*)(ws + WIN_OFF);
    const float* __restrict__ ab = audio + (size_t)b * AUDIO_LEN;
    const int base = tf * 512 - 1024;

    const f2 wtree0 = TWv[2 * t];             // W_1024^t
    const f2 wtree1 = TWv[32 * (t >> 4)];     // W_64^(t>>4)
    const f2 wt     = TWv[t];                 // W_2048^t

    f2 x[16];
    if (tf >= 2 && tf <= 2558) {
        const f2* __restrict__ a2 = (const f2*)(ab + base);
#pragma unroll
        for (int l = 0; l < 16; l++) {
            const int p = t + 64 * l;
            x[l] = a2[p] * W2v[p];
        }
    } else {
#pragma unroll
        for (int l = 0; l < 16; l++) {
            const int p = t + 64 * l;
            int j0 = base + 2 * p, j1 = j0 + 1;
            j0 = (j0 < 0) ? -j0 : ((j0 >= AUDIO_LEN) ? 2 * AUDIO_LEN - 2 - j0 : j0);
            j1 = (j1 < 0) ? -j1 : ((j1 >= AUDIO_LEN) ? 2 * AUDIO_LEN - 2 - j1 : j1);
            f2 v; v.x = ab[j0]; v.y = ab[j1];
            x[l] = v * W2v[p];
        }
    }

    // ---- stage 0: radix-16, m=1 ----
    dft16v(x);
    twiddle15v(x, wtree0);
    {
        const int m  = (t ^ (t >> 3)) & 7;
        const int bi = 16 * t;
#pragma unroll
        for (int dp = 0; dp < 8; dp++) {
            const int q = bi + 2 * (dp ^ m);
            A[q]     = x[2 * dp];
            A[q + 1] = x[2 * dp + 1];
        }
    }
    asm volatile("s_waitcnt lgkmcnt(0)" ::: "memory");
    __builtin_amdgcn_sched_barrier(0);

    int adr[16];
#pragma unroll
    for (int s = 0; s < 16; s++) {
        const int p = t + 64 * s;
        adr[s] = p ^ (((((p >> 4) ^ (p >> 7)) & 7)) << 1);
    }

    // ---- stage 1: radix-16, m=16 ----
#pragma unroll
    for (int l = 0; l < 16; l++) x[l] = A[adr[l]];
    dft16v(x);
    twiddle15v(x, wtree1);
    {
        const int basei = (t & 15) + 256 * (t >> 4);
#pragma unroll
        for (int d = 0; d < 16; d++) {
            const int p = basei + 16 * d;
            A[p ^ (((((p >> 4) ^ (p >> 7)) & 7)) << 1)] = x[d];
        }
    }
    asm volatile("s_waitcnt lgkmcnt(0)" ::: "memory");
    __builtin_amdgcn_sched_barrier(0);

    // ---- stage 2: radix-4, in place ----
#pragma unroll
    for (int s = 0; s < 16; s++) x[s] = A[adr[s]];
#pragma unroll
    for (int w = 0; w < 4; w++)
        DFT4V(x[w], x[w + 4], x[w + 8], x[w + 12],
              x[w], x[w + 4], x[w + 8], x[w + 12]);

    // ---- untangle, bins 0..575 ----
    const float CS[NSU] = { 1.0f,               0.98078528040323f,  0.92387953251129f,  0.83146961230255f,
                            0.70710678118655f,  0.55557023301960f,  0.38268343236509f,  0.19509032201613f,
                            0.0f };
    const float SN[NSU] = { 0.0f,               0.19509032201613f,  0.38268343236509f,  0.55557023301960f,
                            0.70710678118655f,  0.83146961230255f,  0.92387953251129f,  0.98078528040323f,
                            1.0f };

    const int src = (64 - t) & 63;
    f2 rt; rt.x = wt.y; rt.y = -wt.x;
    _Float16* __restrict__ mrow = mag + (size_t)ft * MROW;
#pragma unroll
    for (int s = 0; s < NSU; s++) {
        float ux = __shfl(x[15 - s].x, src, 64);
        float uy = __shfl(x[15 - s].y, src, 64);
        if (t == 0) { ux = x[(16 - s) & 15].x; uy = x[(16 - s) & 15].y; }
        const f2 z = x[s];
        f2 cu; cu.x = ux; cu.y = -uy;
        const f2 a = z + cu;
        const f2 d = z - cu;
        f2 pp; pp.x = d.y; pp.y = -d.x;
        const f2 wk = wt * CS[s] + rt * SN[s];
        const f2 Y = a + cmul(wk, pp);
        mrow[t + 64 * s] = (_Float16)sqrtf(fmaf(Y.x, Y.x, Y.y * Y.y));
    }
}

// ======== A/B variant 2: LDS twiddle table + shfl broadcast (R16 structure) ========
__global__ __launch_bounds__(128) void fft_table(const float* __restrict__ audio,
                                                 const float* __restrict__ ws,
                                                 _Float16* __restrict__ mag,
                                                 int ft_base) {
    __shared__ f2 Abuf[2][HALF_N];     // 8 KB per wave, wave-private
    __shared__ f2 TP0s[960];           // 7.5 KB, block-shared, read-only after init

    const int t    = threadIdx.x & 63;
    const int wave = threadIdx.x >> 6;
    const int ft   = ft_base + blockIdx.x * 2 + wave;
    const int b    = ft / NFRAMES;
    const int tf   = ft - b * NFRAMES;
    f2* __restrict__ A = Abuf[wave];

    const f2* __restrict__ TWv  = (const f2*)(ws + TW_OFF);
    const f2* __restrict__ W2v  = (const f2*)(ws + WIN_OFF);
    const f2* __restrict__ TP0g = (const f2*)(ws + TP0_OFF);
    const float* __restrict__ ab = audio + (size_t)b * AUDIO_LEN;
    const int base = tf * 512 - 1024;

    for (int i = threadIdx.x; i < 960; i += 128) TP0s[i] = TP0g[i];
    __syncthreads();

    const f2 wt = TWv[t];

    f2 x[16];
    if (tf >= 2 && tf <= 2558) {
        const f2* __restrict__ a2 = (const f2*)(ab + base);
#pragma unroll
        for (int l = 0; l < 16; l++) {
            const int p = t + 64 * l;
            x[l] = a2[p] * W2v[p];
        }
    } else {
#pragma unroll
        for (int l = 0; l < 16; l++) {
            const int p = t + 64 * l;
            int j0 = base + 2 * p, j1 = j0 + 1;
            j0 = (j0 < 0) ? -j0 : ((j0 >= AUDIO_LEN) ? 2 * AUDIO_LEN - 2 - j0 : j0);
            j1 = (j1 < 0) ? -j1 : ((j1 >= AUDIO_LEN) ? 2 * AUDIO_LEN - 2 - j1 : j1);
            f2 v; v.x = ab[j0]; v.y = ab[j1];
            x[l] = v * W2v[p];
        }
    }

    f2 wp[15];
#pragma unroll
    for (int i = 0; i < 15; i++) wp[i] = TP0s[i * 64 + t];

    // ---- stage 0: radix-16, m=1 ----
    dft16v(x);
#pragma unroll
    for (int i = 1; i < 16; i++) x[i] = cmul(x[i], wp[i - 1]);
    {
        const int m  = (t ^ (t >> 3)) & 7;
        const int bi = 16 * t;
#pragma unroll
        for (int dp = 0; dp < 8; dp++) {
            const int q = bi + 2 * (dp ^ m);
            A[q]     = x[2 * dp];
            A[q + 1] = x[2 * dp + 1];
        }
    }

    // stage-1 twiddles: in-place lane broadcast from lane (t&48)
    {
        const int srcb = t & 48;
#pragma unroll
        for (int i = 0; i < 15; i++) {
            wp[i].x = __shfl(wp[i].x, srcb, 64);
            wp[i].y = __shfl(wp[i].y, srcb, 64);
        }
    }

    asm volatile("s_waitcnt lgkmcnt(0)" ::: "memory");
    __builtin_amdgcn_sched_barrier(0);

    int adr[16];
#pragma unroll
    for (int s = 0; s < 16; s++) {
        const int p = t + 64 * s;
        adr[s] = p ^ (((((p >> 4) ^ (p >> 7)) & 7)) << 1);
    }

    // ---- stage 1: radix-16, m=16 ----
#pragma unroll
    for (int l = 0; l < 16; l++) x[l] = A[adr[l]];
    dft16v(x);
#pragma unroll
    for (int i = 1; i < 16; i++) x[i] = cmul(x[i], wp[i - 1]);
    {
        const int basei = (t & 15) + 256 * (t >> 4);
#pragma unroll
        for (int d = 0; d < 16; d++) {
            const int p = basei + 16 * d;
            A[p ^ (((((p >> 4) ^ (p >> 7)) & 7)) << 1)] = x[d];
        }
    }
    asm volatile("s_waitcnt lgkmcnt(0)" ::: "memory");
    __builtin_amdgcn_sched_barrier(0);

    // ---- stage 2: radix-4, in place ----
#pragma unroll
    for (int s = 0; s < 16; s++) x[s] = A[adr[s]];
#pragma unroll
    for (int w = 0; w < 4; w++)
        DFT4V(x[w], x[w + 4], x[w + 8], x[w + 12],
              x[w], x[w + 4], x[w + 8], x[w + 12]);

    // ---- untangle, bins 0..575 ----
    const float CS[NSU] = { 1.0f,               0.98078528040323f,  0.92387953251129f,  0.83146961230255f,
                            0.70710678118655f,  0.55557023301960f,  0.38268343236509f,  0.19509032201613f,
                            0.0f };
    const float SN[NSU] = { 0.0f,               0.19509032201613f,  0.38268343236509f,  0.55557023301960f,
                            0.70710678118655f,  0.83146961230255f,  0.92387953251129f,  0.98078528040323f,
                            1.0f };

    const int src = (64 - t) & 63;
    f2 rt; rt.x = wt.y; rt.y = -wt.x;
    _Float16* __restrict__ mrow = mag + (size_t)ft * MROW;
#pragma unroll
    for (int s = 0; s < NSU; s++) {
        float ux = __shfl(x[15 - s].x, src, 64);
        float uy = __shfl(x[15 - s].y, src, 64);
        if (t == 0) { ux = x[(16 - s) & 15].x; uy = x[(16 - s) & 15].y; }
        const f2 z = x[s];
        f2 cu; cu.x = ux; cu.y = -uy;
        const f2 a = z + cu;
        const f2 d = z - cu;
        f2 pp; pp.x = d.y; pp.y = -d.x;
        const f2 wk = wt * CS[s] + rt * SN[s];
        const f2 Y = a + cmul(wk, pp);
        mrow[t + 64 * s] = (_Float16)sqrtf(fmaf(Y.x, Y.x, Y.y * Y.y));
    }
}

// ---------------- MFMA projection: out[96,NT] = Wf * mag^T ----------------
__global__ __launch_bounds__(256) void proj_kernel(const float* __restrict__ ws,
                                                   const _Float16* __restrict__ mag,
                                                   float* __restrict__ out) {
    __shared__ __align__(16) _Float16 As[2][4096];   // [cur][slot=mt*64+lane][8]
    __shared__ __align__(16) _Float16 Bs[2][4096];   // [cur][slot=fr*4+kg][8]

    const int tid  = threadIdx.x;
    const int lane = tid & 63;
    const int w    = tid >> 6;
    const int ft0  = blockIdx.x * 128;

    const _Float16* __restrict__ wf = (const _Float16*)(ws + WF_OFF);

    const int fr = tid >> 2, kg = tid & 3;
    int ftc0 = ft0 + fr;       if (ftc0 >= NT) ftc0 = NT - 1;
    int ftc1 = ft0 + fr + 64;  if (ftc1 >= NT) ftc1 = NT - 1;
    const _Float16* bsrc0 = mag + (size_t)ftc0 * MROW + kg * 8;
    const _Float16* bsrc1 = mag + (size_t)ftc1 * MROW + kg * 8;

#define STAGE(nb, ck)  do {                                                   \
        const _Float16* asrc = wf + (size_t)(ck) * 4096;                      \
        gll16(asrc + (size_t)tid * 8,         &As[nb][tid * 8]);              \
        gll16(asrc + (size_t)(tid + 256) * 8, &As[nb][(tid + 256) * 8]);      \
        gll16(bsrc0 + (ck) * 32,              &Bs[nb][tid * 8]);              \
        gll16(bsrc1 + (ck) * 32,              &Bs[nb][(tid + 256) * 8]);      \
    } while (0)

    f32x4 acc[6][2];
#pragma unroll
    for (int mt = 0; mt < 6; mt++)
#pragma unroll
        for (int nt = 0; nt < 2; nt++) acc[mt][nt] = (f32x4)0.0f;

    STAGE(0, 0);
    int cur = 0;
    for (int ck = 0; ck < NCH_USED; ck++) {
        if (ck + 1 < NCH_USED) {
            STAGE(cur ^ 1, ck + 1);
            asm volatile("s_waitcnt vmcnt(4)" ::: "memory");
        } else {
            asm volatile("s_waitcnt vmcnt(0)" ::: "memory");
        }
        __builtin_amdgcn_s_barrier();

        h8 a[6], bb[2];
#pragma unroll
        for (int mt = 0; mt < 6; mt++)
            a[mt] = *(const h8*)&As[cur][(mt * 64 + lane) * 8];
#pragma unroll
        for (int nt = 0; nt < 2; nt++) {
            const int slot = (w * 32 + nt * 16 + (lane & 15)) * 4 + (lane >> 4);
            bb[nt] = *(const h8*)&Bs[cur][slot * 8];
        }
#pragma unroll
        for (int mt = 0; mt < 6; mt++)
#pragma unroll
            for (int nt = 0; nt < 2; nt++)
                acc[mt][nt] = __builtin_amdgcn_mfma_f32_16x16x32_f16(a[mt], bb[nt], acc[mt][nt], 0, 0, 0);

        asm volatile("" ::: "memory");
        __builtin_amdgcn_s_barrier();
        cur ^= 1;
    }
#undef STAGE

    const int fcol = lane & 15, frow = lane >> 4;
#pragma unroll
    for (int nt = 0; nt < 2; nt++) {
        const int ft = ft0 + w * 32 + nt * 16 + fcol;
        if (ft < NT) {
            const int b = ft / NFRAMES;
            const int t = ft - b * NFRAMES;
#pragma unroll
            for (int mt = 0; mt < 6; mt++)
#pragma unroll
                for (int r = 0; r < 4; r++) {
                    const int k = mt * 16 + frow * 4 + r;
                    if (k < NK)
                        out[((size_t)b * NK + k) * NFRAMES + t] = log10f(acc[mt][nt][r] + 1e-10f);
                }
        }
    }
}

extern "C" void kernel_launch(void* const* d_in, const int* in_sizes, int n_in,
                              void* d_out, int out_size, void* d_ws, size_t ws_size,
                              hipStream_t stream) {
    const float* audio = (const float*)d_in[0];
    float* out = (float*)d_out;
    float* ws  = (float*)d_ws;
    _Float16* mag = (_Float16*)((char*)d_ws + MAG_OFF_B);

    hipLaunchKernelGGL(init_tables_kernel, dim3(528), dim3(256), 0, stream, ws);
    // within-session A/B: tree variant on first half, table variant on second
    hipLaunchKernelGGL(fft_tree,  dim3(NHALF / 2), dim3(128), 0, stream, audio, ws, mag, 0);
    hipLaunchKernelGGL(fft_table, dim3(NHALF / 2), dim3(128), 0, stream, audio, ws, mag, NHALF);
    hipLaunchKernelGGL(proj_kernel, dim3((NT + 127) / 128), dim3(256), 0, stream, ws, mag, out);
}

// Round 19
// 119.717 us; speedup vs baseline: 1.0684x; 1.0684x over previous
//
#include <hip/hip_runtime.h>
#include <hip/hip_bf16.h>
#include <math.h>

#define AUDIO_LEN 1310720
#define NBATCH    16
#define NFRAMES   2561
#define NT        (NBATCH * NFRAMES)   // 40976
#define NFFT      2048
#define HALF_N    1024
#define NK        84
#define NF        1025
#define MROW      1056                 // padded mag row stride (f16)
#define NCH       33                   // weight table extent (33*32 = 1056)
#define NCH_USED  18                   // f >= 576 skipped (w_83 <= 1.7e-4 -> ~4e-5 log10 err)
#define NSU       9                    // untangle bins t+64s, s<9 -> 0..575

// ws layout: float offsets for tables, byte offset for mag
#define TW_OFF   0                     // float2[1025]: TW[k] = e^{-i pi k/1024}
#define WIN_OFF  2052                  // float[2048]  (pre-scaled by 0.25)
#define WF_OFF   4104                  // _Float16[33*512*8] pre-fragmented W
#define MAG_OFF_B 294912               // f16 mag[NT][MROW], 16B aligned

typedef _Float16 h8    __attribute__((ext_vector_type(8)));
typedef float    f32x4 __attribute__((ext_vector_type(4)));
typedef float    f2    __attribute__((ext_vector_type(2)));

__device__ __forceinline__ void gll16(const void* src, void* dst) {
    __builtin_amdgcn_global_load_lds(
        (const __attribute__((address_space(1))) void*)src,
        (__attribute__((address_space(3))) void*)dst, 16, 0, 0);
}

// packed complex mul
__device__ __forceinline__ f2 cmul(f2 a, f2 b) {
    f2 t = a.yy * b.yx;        // {ay*by, ay*bx}
    f2 m; m.x = -t.x; m.y = t.y;
    return a.xx * b + m;       // pk_fma
}

#define DFT4V(p0, p1, p2, p3, y0, y1, y2, y3) do {                       \
    const f2 u0 = (p0) + (p2), u1 = (p0) - (p2);                         \
    const f2 u2 = (p1) + (p3), u3 = (p1) - (p3);                         \
    f2 r; r.x = u3.y; r.y = -u3.x;        /* -i * u3 */                  \
    (y0) = u0 + u2; (y2) = u0 - u2;                                      \
    (y1) = u1 + r;  (y3) = u1 - r;                                       \
} while (0)

// DFT-16 in registers: two radix-4 levels + constant omega16 twiddles
__device__ __forceinline__ void dft16v(f2* v) {
    const float C = 0.92387953251128674f;   // cos(pi/8)
    const float S = 0.38268343236508978f;   // sin(pi/8)
    const float H = 0.70710678118654752f;
    const f2 W1 = {C, -S}, W2c = {H, -H}, W3 = {S, -C}, W6 = {-H, -H}, W9 = {-C, S};
    f2 A[16];
#pragma unroll
    for (int b = 0; b < 4; b++)
        DFT4V(v[b], v[b + 4], v[b + 8], v[b + 12],
              A[b * 4 + 0], A[b * 4 + 1], A[b * 4 + 2], A[b * 4 + 3]);
    A[5]  = cmul(A[5],  W1);
    A[6]  = cmul(A[6],  W2c);
    A[7]  = cmul(A[7],  W3);
    A[9]  = cmul(A[9],  W2c);
    { f2 r; r.x = A[10].y; r.y = -A[10].x; A[10] = r; }   // * -i
    A[11] = cmul(A[11], W6);
    A[13] = cmul(A[13], W3);
    A[14] = cmul(A[14], W6);
    A[15] = cmul(A[15], W9);
#pragma unroll
    for (int d1 = 0; d1 < 4; d1++)
        DFT4V(A[0 + d1], A[4 + d1], A[8 + d1], A[12 + d1],
              v[d1], v[d1 + 4], v[d1 + 8], v[d1 + 12]);
}

// v[i] *= w1^i, i=1..15 (packed power tree; zero memory traffic)
__device__ __forceinline__ void twiddle15v(f2* v, f2 w1) {
    f2 wp[16];
    wp[1]  = w1;
    wp[2]  = cmul(w1, w1);
    wp[3]  = cmul(wp[2], w1);
    wp[4]  = cmul(wp[2], wp[2]);
    wp[5]  = cmul(wp[4], w1);
    wp[6]  = cmul(wp[3], wp[3]);
    wp[7]  = cmul(wp[4], wp[3]);
    wp[8]  = cmul(wp[4], wp[4]);
    wp[9]  = cmul(wp[8], w1);
    wp[10] = cmul(wp[5], wp[5]);
    wp[11] = cmul(wp[8], wp[3]);
    wp[12] = cmul(wp[6], wp[6]);
    wp[13] = cmul(wp[8], wp[5]);
    wp[14] = cmul(wp[7], wp[7]);
    wp[15] = cmul(wp[8], wp[7]);
#pragma unroll
    for (int i = 1; i < 16; i++) v[i] = cmul(v[i], wp[i]);
}

__global__ __launch_bounds__(256) void init_tables_kernel(float* __restrict__ ws) {
    int i = blockIdx.x * 256 + threadIdx.x;
    // pre-fragmented f16 weights: [ck][slot=mt*64+lane (384..511 zero-pad)][8]
    if (i < NCH * 512 * 8) {
        int i8 = i & 7;
        int c  = i >> 3;
        int ck = c >> 9;
        int cc = c & 511;
        int mt = cc >> 6;
        int l  = cc & 63;
        int k  = mt * 16 + (l & 15);
        int f  = ck * 32 + (l >> 4) * 8 + i8;
        float w = 0.0f;
        if (cc < 384 && k < NK && f < NF) {
            float sf = (float)f * (22050.0f / 2048.0f);
            float cf = 27.5f * exp2f((float)k * (1.0f / 12.0f));
            w = expf(-fabsf(sf - cf) / (0.1f * cf));
        }
        ((_Float16*)(ws + WF_OFF))[i] = (_Float16)w;
    }
    if (i <= HALF_N) {
        double ang = -2.0 * M_PI * (double)i / 2048.0;
        ws[TW_OFF + 2 * i]     = (float)cos(ang);
        ws[TW_OFF + 2 * i + 1] = (float)sin(ang);
    }
    if (i < NFFT) {
        double ang = 2.0 * M_PI * (double)i / 2048.0;
        ws[WIN_OFF + i] = (float)(0.25 * (1.0 - cos(ang)));   // 0.5*Hann: folds mag 0.5
    }
}

// ---- 2 waves/block, 1 wave = 1 frame; 1024-pt FFT, 2 LDS round-trips ----
// LDS discipline: all accesses f2-typed (no type-pun) and an explicit
// lgkmcnt(0)+sched_barrier fence at each write-phase -> read-phase boundary.
__global__ __launch_bounds__(128) void fft_kernel(const float* __restrict__ audio,
                                                  const float* __restrict__ ws,
                                                  _Float16* __restrict__ mag) {
    __shared__ f2 Abuf[2][HALF_N];     // 8 KB per wave, wave-private

    const int t    = threadIdx.x & 63;
    const int wave = threadIdx.x >> 6;
    const int ft   = blockIdx.x * 2 + wave;
    const int b    = ft / NFRAMES;
    const int tf   = ft - b * NFRAMES;
    f2* __restrict__ A = Abuf[wave];

    const f2* __restrict__ TWv = (const f2*)(ws + TW_OFF);
    const f2* __restrict__ W2v = (const f2*)(ws + WIN_OFF);
    const float* __restrict__ ab = audio + (size_t)b * AUDIO_LEN;
    const int base = tf * 512 - 1024;

    // hoisted twiddle bases (all global loads at top)
    const f2 wtree0 = TWv[2 * t];             // W_1024^t
    const f2 wtree1 = TWv[32 * (t >> 4)];     // W_64^(t>>4)
    const f2 wt     = TWv[t];                 // W_2048^t

    // load + 0.5*window + even/odd complex pack: x[l] = z[t + 64l]
    f2 x[16];
    if (tf >= 2 && tf <= 2558) {
        const f2* __restrict__ a2 = (const f2*)(ab + base);
#pragma unroll
        for (int l = 0; l < 16; l++) {
            const int p = t + 64 * l;
            x[l] = a2[p] * W2v[p];
        }
    } else {
#pragma unroll
        for (int l = 0; l < 16; l++) {
            const int p = t + 64 * l;
            int j0 = base + 2 * p, j1 = j0 + 1;
            j0 = (j0 < 0) ? -j0 : ((j0 >= AUDIO_LEN) ? 2 * AUDIO_LEN - 2 - j0 : j0);
            j1 = (j1 < 0) ? -j1 : ((j1 >= AUDIO_LEN) ? 2 * AUDIO_LEN - 2 - j1 : j1);
            f2 v; v.x = ab[j0]; v.y = ab[j1];
            x[l] = v * W2v[p];
        }
    }

    // ---- stage 0: radix-16, m=1 ----
    dft16v(x);
    twiddle15v(x, wtree0);
    {
        const int m  = (t ^ (t >> 3)) & 7;   // XOR swizzle (pair-slot granularity)
        const int bi = 16 * t;               // f2 index base
#pragma unroll
        for (int dp = 0; dp < 8; dp++) {
            const int q = bi + 2 * (dp ^ m);
            A[q]     = x[2 * dp];
            A[q + 1] = x[2 * dp + 1];
        }
    }
    // fence: stage-0 writes must complete before stage-1 reads issue
    asm volatile("s_waitcnt lgkmcnt(0)" ::: "memory");
    __builtin_amdgcn_sched_barrier(0);

    // swizzled f2 addresses for the stride-64 read pattern (reused by stage 2)
    int adr[16];
#pragma unroll
    for (int s = 0; s < 16; s++) {
        const int p = t + 64 * s;
        adr[s] = p ^ (((((p >> 4) ^ (p >> 7)) & 7)) << 1);
    }

    // ---- stage 1: radix-16, m=16 ----
#pragma unroll
    for (int l = 0; l < 16; l++) x[l] = A[adr[l]];
    dft16v(x);
    twiddle15v(x, wtree1);
    {
        const int basei = (t & 15) + 256 * (t >> 4);
#pragma unroll
        for (int d = 0; d < 16; d++) {
            const int p = basei + 16 * d;
            A[p ^ (((((p >> 4) ^ (p >> 7)) & 7)) << 1)] = x[d];
        }
    }
    // fence: stage-1 writes must complete before stage-2 reads issue
    asm volatile("s_waitcnt lgkmcnt(0)" ::: "memory");
    __builtin_amdgcn_sched_barrier(0);

    // ---- stage 2: radix-4, m=256, no twiddles, in place; lane holds Z[t+64s] ----
#pragma unroll
    for (int s = 0; s < 16; s++) x[s] = A[adr[s]];
#pragma unroll
    for (int w = 0; w < 4; w++)
        DFT4V(x[w], x[w + 4], x[w + 8], x[w + 12],
              x[w], x[w + 4], x[w + 8], x[w + 12]);

    // ---- rfft untangle via lane exchange, bins 0..575 only (proj reads f<576) ----
    const float CS[NSU] = { 1.0f,               0.98078528040323f,  0.92387953251129f,  0.83146961230255f,
                            0.70710678118655f,  0.55557023301960f,  0.38268343236509f,  0.19509032201613f,
                            0.0f };
    const float SN[NSU] = { 0.0f,               0.19509032201613f,  0.38268343236509f,  0.55557023301960f,
                            0.70710678118655f,  0.83146961230255f,  0.92387953251129f,  0.98078528040323f,
                            1.0f };

    const int src = (64 - t) & 63;
    f2 rt; rt.x = wt.y; rt.y = -wt.x;         // -i * wt
    _Float16* __restrict__ mrow = mag + (size_t)ft * MROW;
#pragma unroll
    for (int s = 0; s < NSU; s++) {
        float ux = __shfl(x[15 - s].x, src, 64);
        float uy = __shfl(x[15 - s].y, src, 64);
        if (t == 0) { ux = x[(16 - s) & 15].x; uy = x[(16 - s) & 15].y; }
        const f2 z = x[s];
        f2 cu; cu.x = ux; cu.y = -uy;            // conj(u)
        const f2 a = z + cu;
        const f2 d = z - cu;
        f2 pp; pp.x = d.y; pp.y = -d.x;          // -i * d
        const f2 wk = wt * CS[s] + rt * SN[s];   // wt * e^{-i pi s/16}
        const f2 Y = a + cmul(wk, pp);           // = X[k] (window pre-halved)
        mrow[t + 64 * s] = (_Float16)sqrtf(fmaf(Y.x, Y.x, Y.y * Y.y));
    }
}

// ---------------- MFMA projection: out[96,NT] = Wf * mag^T ----------------
__global__ __launch_bounds__(256) void proj_kernel(const float* __restrict__ ws,
                                                   const _Float16* __restrict__ mag,
                                                   float* __restrict__ out) {
    __shared__ __align__(16) _Float16 As[2][4096];   // [cur][slot=mt*64+lane][8]
    __shared__ __align__(16) _Float16 Bs[2][4096];   // [cur][slot=fr*4+kg][8]

    const int tid  = threadIdx.x;
    const int lane = tid & 63;
    const int w    = tid >> 6;
    const int ft0  = blockIdx.x * 128;

    const _Float16* __restrict__ wf = (const _Float16*)(ws + WF_OFF);

    const int fr = tid >> 2, kg = tid & 3;
    int ftc0 = ft0 + fr;       if (ftc0 >= NT) ftc0 = NT - 1;
    int ftc1 = ft0 + fr + 64;  if (ftc1 >= NT) ftc1 = NT - 1;
    const _Float16* bsrc0 = mag + (size_t)ftc0 * MROW + kg * 8;
    const _Float16* bsrc1 = mag + (size_t)ftc1 * MROW + kg * 8;

#define STAGE(nb, ck)  do {                                                   \
        const _Float16* asrc = wf + (size_t)(ck) * 4096;                      \
        gll16(asrc + (size_t)tid * 8,         &As[nb][tid * 8]);              \
        gll16(asrc + (size_t)(tid + 256) * 8, &As[nb][(tid + 256) * 8]);      \
        gll16(bsrc0 + (ck) * 32,              &Bs[nb][tid * 8]);              \
        gll16(bsrc1 + (ck) * 32,              &Bs[nb][(tid + 256) * 8]);      \
    } while (0)

    f32x4 acc[6][2];
#pragma unroll
    for (int mt = 0; mt < 6; mt++)
#pragma unroll
        for (int nt = 0; nt < 2; nt++) acc[mt][nt] = (f32x4)0.0f;

    STAGE(0, 0);
    int cur = 0;
    for (int ck = 0; ck < NCH_USED; ck++) {
        if (ck + 1 < NCH_USED) {
            STAGE(cur ^ 1, ck + 1);
            asm volatile("s_waitcnt vmcnt(4)" ::: "memory");
        } else {
            asm volatile("s_waitcnt vmcnt(0)" ::: "memory");
        }
        __builtin_amdgcn_s_barrier();

        h8 a[6], bb[2];
#pragma unroll
        for (int mt = 0; mt < 6; mt++)
            a[mt] = *(const h8*)&As[cur][(mt * 64 + lane) * 8];
#pragma unroll
        for (int nt = 0; nt < 2; nt++) {
            const int slot = (w * 32 + nt * 16 + (lane & 15)) * 4 + (lane >> 4);
            bb[nt] = *(const h8*)&Bs[cur][slot * 8];
        }
#pragma unroll
        for (int mt = 0; mt < 6; mt++)
#pragma unroll
            for (int nt = 0; nt < 2; nt++)
                acc[mt][nt] = __builtin_amdgcn_mfma_f32_16x16x32_f16(a[mt], bb[nt], acc[mt][nt], 0, 0, 0);

        asm volatile("" ::: "memory");
        __builtin_amdgcn_s_barrier();
        cur ^= 1;
    }
#undef STAGE

    const int fcol = lane & 15, frow = lane >> 4;
#pragma unroll
    for (int nt = 0; nt < 2; nt++) {
        const int ft = ft0 + w * 32 + nt * 16 + fcol;
        if (ft < NT) {
            const int b = ft / NFRAMES;
            const int t = ft - b * NFRAMES;
#pragma unroll
            for (int mt = 0; mt < 6; mt++)
#pragma unroll
                for (int r = 0; r < 4; r++) {
                    const int k = mt * 16 + frow * 4 + r;
                    if (k < NK)
                        out[((size_t)b * NK + k) * NFRAMES + t] = log10f(acc[mt][nt][r] + 1e-10f);
                }
        }
    }
}

extern "C" void kernel_launch(void* const* d_in, const int* in_sizes, int n_in,
                              void* d_out, int out_size, void* d_ws, size_t ws_size,
                              hipStream_t stream) {
    const float* audio = (const float*)d_in[0];
    float* out = (float*)d_out;
    float* ws  = (float*)d_ws;
    _Float16* mag = (_Float16*)((char*)d_ws + MAG_OFF_B);

    hipLaunchKernelGGL(init_tables_kernel, dim3(528), dim3(256), 0, stream, ws);
    hipLaunchKernelGGL(fft_kernel, dim3(NT / 2), dim3(128), 0, stream, audio, ws, mag);
    hipLaunchKernelGGL(proj_kernel, dim3((NT + 127) / 128), dim3(256), 0, stream, ws, mag, out);
}

// Round 20
// 110.002 us; speedup vs baseline: 1.1628x; 1.0883x over previous
//
#include <hip/hip_runtime.h>
#include <hip/hip_bf16.h>
#include <math.h>

#define AUDIO_LEN 1310720
#define NBATCH    16
#define NFRAMES   2561
#define NT        (NBATCH * NFRAMES)   // 40976
#define NFFT      2048
#define HALF_N    1024
#define NK        84
#define NF        1025
#define MROW      1056                 // padded mag row stride (f16)
#define NCH       33                   // weight table extent (33*32 = 1056)
#define NCH_USED  22                   // f >= 704: w_83 < 3e-6 -> negligible, skipped
#define NSU       11                   // untangle s-range: bins t+64s, s<11 -> 0..703

// ws layout: float offsets for tables, byte offset for mag
#define TW_OFF   0                     // float2[1025]: TW[k] = e^{-i pi k/1024}
#define WIN_OFF  2052                  // float[2048]  (pre-scaled by 0.25)
#define WF_OFF   4104                  // _Float16[33*512*8] pre-fragmented W
#define MAG_OFF_B 294912               // f16 mag[NT][MROW], 16B aligned

typedef _Float16 h8    __attribute__((ext_vector_type(8)));
typedef float    f32x4 __attribute__((ext_vector_type(4)));
typedef float    f2    __attribute__((ext_vector_type(2)));

__device__ __forceinline__ void gll16(const void* src, void* dst) {
    __builtin_amdgcn_global_load_lds(
        (const __attribute__((address_space(1))) void*)src,
        (__attribute__((address_space(3))) void*)dst, 16, 0, 0);
}

// packed complex mul
__device__ __forceinline__ f2 cmul(f2 a, f2 b) {
    f2 t = a.yy * b.yx;        // {ay*by, ay*bx}
    f2 m; m.x = -t.x; m.y = t.y;
    return a.xx * b + m;       // pk_fma
}

#define DFT4V(p0, p1, p2, p3, y0, y1, y2, y3) do {                       \
    const f2 u0 = (p0) + (p2), u1 = (p0) - (p2);                         \
    const f2 u2 = (p1) + (p3), u3 = (p1) - (p3);                         \
    f2 r; r.x = u3.y; r.y = -u3.x;        /* -i * u3 */                  \
    (y0) = u0 + u2; (y2) = u0 - u2;                                      \
    (y1) = u1 + r;  (y3) = u1 - r;                                       \
} while (0)

// DFT-16 in registers: two radix-4 levels + constant omega16 twiddles
__device__ __forceinline__ void dft16v(f2* v) {
    const float C = 0.92387953251128674f;   // cos(pi/8)
    const float S = 0.38268343236508978f;   // sin(pi/8)
    const float H = 0.70710678118654752f;
    const f2 W1 = {C, -S}, W2c = {H, -H}, W3 = {S, -C}, W6 = {-H, -H}, W9 = {-C, S};
    f2 A[16];
#pragma unroll
    for (int b = 0; b < 4; b++)
        DFT4V(v[b], v[b + 4], v[b + 8], v[b + 12],
              A[b * 4 + 0], A[b * 4 + 1], A[b * 4 + 2], A[b * 4 + 3]);
    A[5]  = cmul(A[5],  W1);
    A[6]  = cmul(A[6],  W2c);
    A[7]  = cmul(A[7],  W3);
    A[9]  = cmul(A[9],  W2c);
    { f2 r; r.x = A[10].y; r.y = -A[10].x; A[10] = r; }   // * -i
    A[11] = cmul(A[11], W6);
    A[13] = cmul(A[13], W3);
    A[14] = cmul(A[14], W6);
    A[15] = cmul(A[15], W9);
#pragma unroll
    for (int d1 = 0; d1 < 4; d1++)
        DFT4V(A[0 + d1], A[4 + d1], A[8 + d1], A[12 + d1],
              v[d1], v[d1 + 4], v[d1 + 8], v[d1 + 12]);
}

// v[i] *= w1^i, i=1..15 (packed power tree; zero memory traffic)
__device__ __forceinline__ void twiddle15v(f2* v, f2 w1) {
    f2 wp[16];
    wp[1]  = w1;
    wp[2]  = cmul(w1, w1);
    wp[3]  = cmul(wp[2], w1);
    wp[4]  = cmul(wp[2], wp[2]);
    wp[5]  = cmul(wp[4], w1);
    wp[6]  = cmul(wp[3], wp[3]);
    wp[7]  = cmul(wp[4], wp[3]);
    wp[8]  = cmul(wp[4], wp[4]);
    wp[9]  = cmul(wp[8], w1);
    wp[10] = cmul(wp[5], wp[5]);
    wp[11] = cmul(wp[8], wp[3]);
    wp[12] = cmul(wp[6], wp[6]);
    wp[13] = cmul(wp[8], wp[5]);
    wp[14] = cmul(wp[7], wp[7]);
    wp[15] = cmul(wp[8], wp[7]);
#pragma unroll
    for (int i = 1; i < 16; i++) v[i] = cmul(v[i], wp[i]);
}

__global__ __launch_bounds__(256) void init_tables_kernel(float* __restrict__ ws) {
    int i = blockIdx.x * 256 + threadIdx.x;
    // pre-fragmented f16 weights: [ck][slot=mt*64+lane (384..511 zero-pad)][8]
    if (i < NCH * 512 * 8) {
        int i8 = i & 7;
        int c  = i >> 3;
        int ck = c >> 9;
        int cc = c & 511;
        int mt = cc >> 6;
        int l  = cc & 63;
        int k  = mt * 16 + (l & 15);
        int f  = ck * 32 + (l >> 4) * 8 + i8;
        float w = 0.0f;
        if (cc < 384 && k < NK && f < NF) {
            float sf = (float)f * (22050.0f / 2048.0f);
            float cf = 27.5f * exp2f((float)k * (1.0f / 12.0f));
            w = expf(-fabsf(sf - cf) / (0.1f * cf));
        }
        ((_Float16*)(ws + WF_OFF))[i] = (_Float16)w;
    }
    if (i <= HALF_N) {
        double ang = -2.0 * M_PI * (double)i / 2048.0;
        ws[TW_OFF + 2 * i]     = (float)cos(ang);
        ws[TW_OFF + 2 * i + 1] = (float)sin(ang);
    }
    if (i < NFFT) {
        double ang = 2.0 * M_PI * (double)i / 2048.0;
        ws[WIN_OFF + i] = (float)(0.25 * (1.0 - cos(ang)));   // 0.5*Hann: folds mag 0.5
    }
}

// ---- 2 waves/block, 1 wave = 1 frame; 1024-pt FFT, 2 LDS round-trips ----
// LDS discipline: all accesses f2-typed (no type-pun) and an explicit
// lgkmcnt(0)+sched_barrier fence at each write-phase -> read-phase boundary.
__global__ __launch_bounds__(128) void fft_kernel(const float* __restrict__ audio,
                                                  const float* __restrict__ ws,
                                                  _Float16* __restrict__ mag) {
    __shared__ f2 Abuf[2][HALF_N];     // 8 KB per wave, wave-private

    const int t    = threadIdx.x & 63;
    const int wave = threadIdx.x >> 6;
    const int ft   = blockIdx.x * 2 + wave;
    const int b    = ft / NFRAMES;
    const int tf   = ft - b * NFRAMES;
    f2* __restrict__ A = Abuf[wave];

    const f2* __restrict__ TWv = (const f2*)(ws + TW_OFF);
    const f2* __restrict__ W2v = (const f2*)(ws + WIN_OFF);
    const float* __restrict__ ab = audio + (size_t)b * AUDIO_LEN;
    const int base = tf * 512 - 1024;

    // hoisted twiddle bases (all global loads at top)
    const f2 wtree0 = TWv[2 * t];             // W_1024^t
    const f2 wtree1 = TWv[32 * (t >> 4)];     // W_64^(t>>4)
    const f2 wt     = TWv[t];                 // W_2048^t

    // load + 0.5*window + even/odd complex pack: x[l] = z[t + 64l]
    f2 x[16];
    if (tf >= 2 && tf <= 2558) {
        const f2* __restrict__ a2 = (const f2*)(ab + base);
#pragma unroll
        for (int l = 0; l < 16; l++) {
            const int p = t + 64 * l;
            x[l] = a2[p] * W2v[p];
        }
    } else {
#pragma unroll
        for (int l = 0; l < 16; l++) {
            const int p = t + 64 * l;
            int j0 = base + 2 * p, j1 = j0 + 1;
            j0 = (j0 < 0) ? -j0 : ((j0 >= AUDIO_LEN) ? 2 * AUDIO_LEN - 2 - j0 : j0);
            j1 = (j1 < 0) ? -j1 : ((j1 >= AUDIO_LEN) ? 2 * AUDIO_LEN - 2 - j1 : j1);
            f2 v; v.x = ab[j0]; v.y = ab[j1];
            x[l] = v * W2v[p];
        }
    }

    // ---- stage 0: radix-16, m=1 ----
    dft16v(x);
    twiddle15v(x, wtree0);
    {
        const int m  = (t ^ (t >> 3)) & 7;   // XOR swizzle (pair-slot granularity)
        const int bi = 16 * t;               // f2 index base
#pragma unroll
        for (int dp = 0; dp < 8; dp++) {
            const int q = bi + 2 * (dp ^ m);
            A[q]     = x[2 * dp];
            A[q + 1] = x[2 * dp + 1];
        }
    }
    // fence: stage-0 writes must complete before stage-1 reads issue
    asm volatile("s_waitcnt lgkmcnt(0)" ::: "memory");
    __builtin_amdgcn_sched_barrier(0);

    // swizzled f2 addresses for the stride-64 read pattern (reused by stage 2)
    int adr[16];
#pragma unroll
    for (int s = 0; s < 16; s++) {
        const int p = t + 64 * s;
        adr[s] = p ^ (((((p >> 4) ^ (p >> 7)) & 7)) << 1);
    }

    // ---- stage 1: radix-16, m=16 ----
#pragma unroll
    for (int l = 0; l < 16; l++) x[l] = A[adr[l]];
    dft16v(x);
    twiddle15v(x, wtree1);
    {
        const int basei = (t & 15) + 256 * (t >> 4);
#pragma unroll
        for (int d = 0; d < 16; d++) {
            const int p = basei + 16 * d;
            A[p ^ (((((p >> 4) ^ (p >> 7)) & 7)) << 1)] = x[d];
        }
    }
    // fence: stage-1 writes must complete before stage-2 reads issue
    asm volatile("s_waitcnt lgkmcnt(0)" ::: "memory");
    __builtin_amdgcn_sched_barrier(0);

    // ---- stage 2: radix-4, m=256, no twiddles, in place; lane holds Z[t+64s] ----
#pragma unroll
    for (int s = 0; s < 16; s++) x[s] = A[adr[s]];
#pragma unroll
    for (int w = 0; w < 4; w++)
        DFT4V(x[w], x[w + 4], x[w + 8], x[w + 12],
              x[w], x[w + 4], x[w + 8], x[w + 12]);

    // ---- rfft untangle via lane exchange, bins 0..703 only (proj reads f<704) ----
    const float CS[NSU] = { 1.0f,               0.98078528040323f,  0.92387953251129f,  0.83146961230255f,
                            0.70710678118655f,  0.55557023301960f,  0.38268343236509f,  0.19509032201613f,
                            0.0f,              -0.19509032201613f, -0.38268343236509f };
    const float SN[NSU] = { 0.0f,               0.19509032201613f,  0.38268343236509f,  0.55557023301960f,
                            0.70710678118655f,  0.83146961230255f,  0.92387953251129f,  0.98078528040323f,
                            1.0f,               0.98078528040323f,  0.92387953251129f };

    const int src = (64 - t) & 63;
    f2 rt; rt.x = wt.y; rt.y = -wt.x;         // -i * wt
    _Float16* __restrict__ mrow = mag + (size_t)ft * MROW;
#pragma unroll
    for (int s = 0; s < NSU; s++) {
        float ux = __shfl(x[15 - s].x, src, 64);
        float uy = __shfl(x[15 - s].y, src, 64);
        if (t == 0) { ux = x[(16 - s) & 15].x; uy = x[(16 - s) & 15].y; }
        const f2 z = x[s];
        f2 cu; cu.x = ux; cu.y = -uy;            // conj(u)
        const f2 a = z + cu;
        const f2 d = z - cu;
        f2 pp; pp.x = d.y; pp.y = -d.x;          // -i * d
        const f2 wk = wt * CS[s] + rt * SN[s];   // wt * e^{-i pi s/16}
        const f2 Y = a + cmul(wk, pp);           // = X[k] (window pre-halved)
        mrow[t + 64 * s] = (_Float16)sqrtf(fmaf(Y.x, Y.x, Y.y * Y.y));
    }
}

// ---------------- MFMA projection: out[96,NT] = Wf * mag^T ----------------
__global__ __launch_bounds__(256) void proj_kernel(const float* __restrict__ ws,
                                                   const _Float16* __restrict__ mag,
                                                   float* __restrict__ out) {
    __shared__ __align__(16) _Float16 As[2][4096];   // [cur][slot=mt*64+lane][8]
    __shared__ __align__(16) _Float16 Bs[2][4096];   // [cur][slot=fr*4+kg][8]

    const int tid  = threadIdx.x;
    const int lane = tid & 63;
    const int w    = tid >> 6;
    const int ft0  = blockIdx.x * 128;

    const _Float16* __restrict__ wf = (const _Float16*)(ws + WF_OFF);

    const int fr = tid >> 2, kg = tid & 3;
    int ftc0 = ft0 + fr;       if (ftc0 >= NT) ftc0 = NT - 1;
    int ftc1 = ft0 + fr + 64;  if (ftc1 >= NT) ftc1 = NT - 1;
    const _Float16* bsrc0 = mag + (size_t)ftc0 * MROW + kg * 8;
    const _Float16* bsrc1 = mag + (size_t)ftc1 * MROW + kg * 8;

#define STAGE(nb, ck)  do {                                                   \
        const _Float16* asrc = wf + (size_t)(ck) * 4096;                      \
        gll16(asrc + (size_t)tid * 8,         &As[nb][tid * 8]);              \
        gll16(asrc + (size_t)(tid + 256) * 8, &As[nb][(tid + 256) * 8]);      \
        gll16(bsrc0 + (ck) * 32,              &Bs[nb][tid * 8]);              \
        gll16(bsrc1 + (ck) * 32,              &Bs[nb][(tid + 256) * 8]);      \
    } while (0)

    f32x4 acc[6][2];
#pragma unroll
    for (int mt = 0; mt < 6; mt++)
#pragma unroll
        for (int nt = 0; nt < 2; nt++) acc[mt][nt] = (f32x4)0.0f;

    STAGE(0, 0);
    int cur = 0;
    for (int ck = 0; ck < NCH_USED; ck++) {
        if (ck + 1 < NCH_USED) {
            STAGE(cur ^ 1, ck + 1);
            asm volatile("s_waitcnt vmcnt(4)" ::: "memory");
        } else {
            asm volatile("s_waitcnt vmcnt(0)" ::: "memory");
        }
        __builtin_amdgcn_s_barrier();

        h8 a[6], bb[2];
#pragma unroll
        for (int mt = 0; mt < 6; mt++)
            a[mt] = *(const h8*)&As[cur][(mt * 64 + lane) * 8];
#pragma unroll
        for (int nt = 0; nt < 2; nt++) {
            const int slot = (w * 32 + nt * 16 + (lane & 15)) * 4 + (lane >> 4);
            bb[nt] = *(const h8*)&Bs[cur][slot * 8];
        }
#pragma unroll
        for (int mt = 0; mt < 6; mt++)
#pragma unroll
            for (int nt = 0; nt < 2; nt++)
                acc[mt][nt] = __builtin_amdgcn_mfma_f32_16x16x32_f16(a[mt], bb[nt], acc[mt][nt], 0, 0, 0);

        asm volatile("" ::: "memory");
        __builtin_amdgcn_s_barrier();
        cur ^= 1;
    }
#undef STAGE

    const int fcol = lane & 15, frow = lane >> 4;
#pragma unroll
    for (int nt = 0; nt < 2; nt++) {
        const int ft = ft0 + w * 32 + nt * 16 + fcol;
        if (ft < NT) {
            const int b = ft / NFRAMES;
            const int t = ft - b * NFRAMES;
#pragma unroll
            for (int mt = 0; mt < 6; mt++)
#pragma unroll
                for (int r = 0; r < 4; r++) {
                    const int k = mt * 16 + frow * 4 + r;
                    if (k < NK)
                        out[((size_t)b * NK + k) * NFRAMES + t] = log10f(acc[mt][nt][r] + 1e-10f);
                }
        }
    }
}

extern "C" void kernel_launch(void* const* d_in, const int* in_sizes, int n_in,
                              void* d_out, int out_size, void* d_ws, size_t ws_size,
                              hipStream_t stream) {
    const float* audio = (const float*)d_in[0];
    float* out = (float*)d_out;
    float* ws  = (float*)d_ws;
    _Float16* mag = (_Float16*)((char*)d_ws + MAG_OFF_B);

    hipLaunchKernelGGL(init_tables_kernel, dim3(528), dim3(256), 0, stream, ws);
    hipLaunchKernelGGL(fft_kernel, dim3(NT / 2), dim3(128), 0, stream, audio, ws, mag);
    hipLaunchKernelGGL(proj_kernel, dim3((NT + 127) / 128), dim3(256), 0, stream, ws, mag, out);
}